// Round 2
// baseline (144.114 us; speedup 1.0000x reference)
//
#include <hip/hip_runtime.h>
#include <hip/hip_bf16.h>

#define B_ 8
#define T_ 2048
#define D_ 256
#define H_ 128

typedef float f32x4 __attribute__((ext_vector_type(4)));
typedef short bf16x8 __attribute__((ext_vector_type(8)));

__device__ __forceinline__ unsigned short f2bf(float f){
  union { float f; unsigned u; } v; v.f = f;
  unsigned u = v.u;
  unsigned r = (u + 0x7FFFu + ((u >> 16) & 1u)) >> 16;
  return (unsigned short)r;
}

// 256-thread (4-wave) block reduce; sbuf must be float[4]
__device__ __forceinline__ float blk_reduce(float v, bool is_max, float* sbuf){
  for(int o = 32; o > 0; o >>= 1){
    float t = __shfl_xor(v, o);
    v = is_max ? fmaxf(v, t) : (v + t);
  }
  int w = threadIdx.x >> 6;
  __syncthreads();
  if((threadIdx.x & 63) == 0) sbuf[w] = v;
  __syncthreads();
  float r = sbuf[0];
  for(int i = 1; i < 4; i++) r = is_max ? fmaxf(r, sbuf[i]) : (r + sbuf[i]);
  return r;
}

// ---------------------------------------------------------------------------
// Kernel 1: QKV projection. grid (256 rowtiles, 3 mats), 256 threads.
// mat0 -> Qsig [B][T][H] f32 (sigmoid applied)
// mat1 -> Kt   [B][H][T] f32 (transposed via LDS)
// mat2 -> Vt   [B][H][T] f32
// ---------------------------------------------------------------------------
__global__ __launch_bounds__(256) void qkv_kernel(
    const float* __restrict__ x,
    const float* __restrict__ Wq, const float* __restrict__ bq,
    const float* __restrict__ Wk, const float* __restrict__ bk,
    const float* __restrict__ Wv, const float* __restrict__ bv,
    float* __restrict__ Qsig, float* __restrict__ Kt, float* __restrict__ Vt)
{
  const int mat = blockIdx.y;
  const int g0  = blockIdx.x * 64;
  const int tid = threadIdx.x;
  const float* W   = (mat == 0) ? Wq : (mat == 1) ? Wk : Wv;
  const float* bia = (mat == 0) ? bq : (mat == 1) ? bk : bv;

  __shared__ __align__(16) short As[64 * 32];
  __shared__ __align__(16) short Ws[128 * 32];
  __shared__ float tbuf[64][129];

  const int w = tid >> 6, lane = tid & 63, rl = lane & 15, kg = lane >> 4;
  f32x4 acc[8];
  for(int i = 0; i < 8; i++) acc[i] = (f32x4){0.f, 0.f, 0.f, 0.f};

  const int c = tid & 31, r8 = tid >> 5;  // staging coords
  for(int kk = 0; kk < 256; kk += 32){
    __syncthreads();
    for(int p = 0; p < 8; p++){
      int rr = r8 + p * 8;
      As[rr * 32 + c] = (short)f2bf(x[(size_t)(g0 + rr) * 256 + kk + c]);
    }
    for(int p = 0; p < 16; p++){
      int hh = r8 + p * 8;
      Ws[hh * 32 + c] = (short)f2bf(W[(size_t)hh * 256 + kk + c]);
    }
    __syncthreads();
    bf16x8 a = *(const bf16x8*)&As[(w * 16 + rl) * 32 + kg * 8];
    for(int cf = 0; cf < 8; cf++){
      bf16x8 bb = *(const bf16x8*)&Ws[(cf * 16 + rl) * 32 + kg * 8];
      acc[cf] = __builtin_amdgcn_mfma_f32_16x16x32_bf16(a, bb, acc[cf], 0, 0, 0);
    }
  }

  const int b = g0 >> 11, t0 = g0 & 2047;
  if(mat == 0){
    for(int cf = 0; cf < 8; cf++){
      int h = cf * 16 + rl;
      float bh = bia[h];
      for(int r = 0; r < 4; r++){
        int tl = w * 16 + kg * 4 + r;
        float v = acc[cf][r] + bh;
        Qsig[(size_t)(g0 + tl) * 128 + h] = 1.f / (1.f + __expf(-v));
      }
    }
  } else {
    for(int cf = 0; cf < 8; cf++){
      int h = cf * 16 + rl;
      float bh = bia[h];
      for(int r = 0; r < 4; r++){
        int tl = w * 16 + kg * 4 + r;
        tbuf[tl][h] = acc[cf][r] + bh;
      }
    }
    __syncthreads();
    float* dst = (mat == 1) ? Kt : Vt;
    int h = tid >> 1, part = tid & 1;
    float* drow = dst + (size_t)(b * 128 + h) * 2048 + t0 + part * 32;
    for(int i = 0; i < 32; i += 4){
      float4 o;
      o.x = tbuf[part * 32 + i + 0][h];
      o.y = tbuf[part * 32 + i + 1][h];
      o.z = tbuf[part * 32 + i + 2][h];
      o.w = tbuf[part * 32 + i + 3][h];
      *(float4*)(drow + i) = o;
    }
  }
}

// ---------------------------------------------------------------------------
// Kernel 2: column softmax over time for K, then Mt[b][h][t]=bf16(eK*V),
// Mt[b][128+h][t]=bf16(eK).  grid = 8*32, 256 threads, 4 h-rows per block.
// ---------------------------------------------------------------------------
__global__ __launch_bounds__(256) void colsm_kernel(
    const float* __restrict__ Kt, const float* __restrict__ Vt,
    unsigned short* __restrict__ Mt)
{
  __shared__ float sbuf[4];
  const int b  = blockIdx.x >> 5;
  const int hg = blockIdx.x & 31;
  const int tid = threadIdx.x;
  for(int i = 0; i < 4; i++){
    int h = hg * 4 + i;
    const float* kr = Kt + (size_t)(b * 128 + h) * 2048;
    const float* vr = Vt + (size_t)(b * 128 + h) * 2048;
    float4 k0 = *(const float4*)(kr + tid * 4);
    float4 k1 = *(const float4*)(kr + tid * 4 + 1024);
    float m = fmaxf(fmaxf(fmaxf(k0.x, k0.y), fmaxf(k0.z, k0.w)),
                    fmaxf(fmaxf(k1.x, k1.y), fmaxf(k1.z, k1.w)));
    m = blk_reduce(m, true, sbuf);
    float s = __expf(k0.x - m) + __expf(k0.y - m) + __expf(k0.z - m) + __expf(k0.w - m)
            + __expf(k1.x - m) + __expf(k1.y - m) + __expf(k1.z - m) + __expf(k1.w - m);
    s = blk_reduce(s, false, sbuf);
    float iz = 1.f / s;
    float4 v0 = *(const float4*)(vr + tid * 4);
    float4 v1 = *(const float4*)(vr + tid * 4 + 1024);
    unsigned short* ekvp = Mt + (size_t)(b * 256 + h) * 2048;
    unsigned short* ekp  = Mt + (size_t)(b * 256 + 128 + h) * 2048;
    ushort4 pv, pe;
    float e;
    e = __expf(__expf(k0.x - m) * iz); pv.x = f2bf(e * v0.x); pe.x = f2bf(e);
    e = __expf(__expf(k0.y - m) * iz); pv.y = f2bf(e * v0.y); pe.y = f2bf(e);
    e = __expf(__expf(k0.z - m) * iz); pv.z = f2bf(e * v0.z); pe.z = f2bf(e);
    e = __expf(__expf(k0.w - m) * iz); pv.w = f2bf(e * v0.w); pe.w = f2bf(e);
    ((ushort4*)ekvp)[tid] = pv;
    ((ushort4*)ekp)[tid]  = pe;
    e = __expf(__expf(k1.x - m) * iz); pv.x = f2bf(e * v1.x); pe.x = f2bf(e);
    e = __expf(__expf(k1.y - m) * iz); pv.y = f2bf(e * v1.y); pe.y = f2bf(e);
    e = __expf(__expf(k1.z - m) * iz); pv.z = f2bf(e * v1.z); pe.z = f2bf(e);
    e = __expf(__expf(k1.w - m) * iz); pv.w = f2bf(e * v1.w); pe.w = f2bf(e);
    ((ushort4*)ekvp)[tid + 256] = pv;
    ((ushort4*)ekp)[tid + 256]  = pe;
  }
}

// ---------------------------------------------------------------------------
// Kernel 3: row softmax stats for adapt_bias. grid = 16384, 256 threads.
// stats[row] = (max, 1/sumexp)
// ---------------------------------------------------------------------------
__global__ __launch_bounds__(256) void rowstats_kernel(
    const float* __restrict__ ab, float* __restrict__ stats)
{
  __shared__ float sbuf[4];
  const size_t row = blockIdx.x;
  const float* r = ab + row * 2048;
  const int tid = threadIdx.x;
  float4 v0 = *(const float4*)(r + tid * 4);
  float4 v1 = *(const float4*)(r + tid * 4 + 1024);
  float m = fmaxf(fmaxf(fmaxf(v0.x, v0.y), fmaxf(v0.z, v0.w)),
                  fmaxf(fmaxf(v1.x, v1.y), fmaxf(v1.z, v1.w)));
  m = blk_reduce(m, true, sbuf);
  float s = __expf(v0.x - m) + __expf(v0.y - m) + __expf(v0.z - m) + __expf(v0.w - m)
          + __expf(v1.x - m) + __expf(v1.y - m) + __expf(v1.z - m) + __expf(v1.w - m);
  s = blk_reduce(s, false, sbuf);
  if(tid == 0){ stats[row * 2] = m; stats[row * 2 + 1] = 1.f / s; }
}

// ---------------------------------------------------------------------------
// Kernel 4: main contraction. C[64 x 256] tile = eab[64 x 2048] @ M[2048 x 256]
// eab computed on the fly from adapt_bias + stats, bf16 in LDS.
// Epilogue: Yt = sigmoid(Q) * num/den  -> bf16.
// grid = 8*32, 512 threads (8 waves: 4 row x 2 col).
// ---------------------------------------------------------------------------
__global__ __launch_bounds__(512) void aft_gemm(
    const float* __restrict__ ab, const float* __restrict__ stats,
    const unsigned short* __restrict__ Mt, const float* __restrict__ Qsig,
    unsigned short* __restrict__ Yt)
{
  __shared__ __align__(16) short As[64 * 32];
  __shared__ __align__(16) short Bs[256 * 32];
  const int b  = blockIdx.x >> 5;
  const int t0 = (blockIdx.x & 31) * 64;
  const int tid = threadIdx.x;
  const int w = tid >> 6, lane = tid & 63, rl = lane & 15, kg = lane >> 4;
  const int wr = w >> 1, wc = w & 1;

  const int sc = tid & 31, sr = tid >> 5;  // staging coords (sr: 0..15)
  float sm[4], siz[4];
  for(int p = 0; p < 4; p++){
    const float* st = stats + (size_t)(b * 2048 + t0 + sr + p * 16) * 2;
    sm[p] = st[0]; siz[p] = st[1];
  }

  f32x4 acc[8];
  for(int i = 0; i < 8; i++) acc[i] = (f32x4){0.f, 0.f, 0.f, 0.f};

  const size_t abrow = (size_t)(b * 2048 + t0);
  const int cr = tid >> 1, part = tid & 1;
  for(int s = 0; s < 2048; s += 32){
    __syncthreads();
    for(int p = 0; p < 4; p++){
      int rr = sr + p * 16;
      float v = ab[(abrow + rr) * 2048 + s + sc];
      float e = __expf(__expf(v - sm[p]) * siz[p]);
      As[rr * 32 + sc] = (short)f2bf(e);
    }
    {
      // each thread copies 16 shorts (32 B) as two uint4 (8-short) chunks
      const unsigned short* src = Mt + (size_t)(b * 256 + cr) * 2048 + s + part * 16;
      *(uint4*)&Bs[cr * 32 + part * 16]     = *(const uint4*)(src);
      *(uint4*)&Bs[cr * 32 + part * 16 + 8] = *(const uint4*)(src + 8);
    }
    __syncthreads();
    bf16x8 a = *(const bf16x8*)&As[(wr * 16 + rl) * 32 + kg * 8];
    for(int cf = 0; cf < 8; cf++){
      int colbase = (cf < 4) ? (wc * 64 + cf * 16) : (128 + wc * 64 + (cf - 4) * 16);
      bf16x8 bb = *(const bf16x8*)&Bs[(colbase + rl) * 32 + kg * 8];
      acc[cf] = __builtin_amdgcn_mfma_f32_16x16x32_bf16(a, bb, acc[cf], 0, 0, 0);
    }
  }

  for(int cf = 0; cf < 4; cf++){
    int h = wc * 64 + cf * 16 + rl;
    for(int r = 0; r < 4; r++){
      int tl = wr * 16 + kg * 4 + r;
      size_t g = (size_t)(b * 2048 + t0 + tl);
      float num = acc[cf][r], den = acc[cf + 4][r];
      float q = Qsig[g * 128 + h];
      Yt[g * 128 + h] = f2bf(q * num / den);
    }
  }
}

// ---------------------------------------------------------------------------
// Kernel 5: output projection out = Yt @ Wp^T + bp. grid = 256, 256 threads.
// ---------------------------------------------------------------------------
__global__ __launch_bounds__(256) void outproj_kernel(
    const unsigned short* __restrict__ Yt, const float* __restrict__ Wp,
    const float* __restrict__ bp, float* __restrict__ out)
{
  __shared__ __align__(16) short As[64 * 32];
  __shared__ __align__(16) short Bs[256 * 32];
  const int g0 = blockIdx.x * 64;
  const int tid = threadIdx.x;
  const int w = tid >> 6, lane = tid & 63, rl = lane & 15, kg = lane >> 4;
  f32x4 acc[16];
  for(int i = 0; i < 16; i++) acc[i] = (f32x4){0.f, 0.f, 0.f, 0.f};

  const int ar = tid >> 2, apart = tid & 3;
  const int c = tid & 31, dr = tid >> 5;
  for(int k = 0; k < 128; k += 32){
    __syncthreads();
    *(uint4*)&As[ar * 32 + apart * 8] =
        *(const uint4*)(Yt + (size_t)(g0 + ar) * 128 + k + apart * 8);
    for(int p = 0; p < 32; p++){
      int d = dr + p * 8;
      Bs[d * 32 + c] = (short)f2bf(Wp[(size_t)d * 128 + k + c]);
    }
    __syncthreads();
    bf16x8 a = *(const bf16x8*)&As[(w * 16 + rl) * 32 + kg * 8];
    for(int cf = 0; cf < 16; cf++){
      bf16x8 bb = *(const bf16x8*)&Bs[(cf * 16 + rl) * 32 + kg * 8];
      acc[cf] = __builtin_amdgcn_mfma_f32_16x16x32_bf16(a, bb, acc[cf], 0, 0, 0);
    }
  }
  for(int cf = 0; cf < 16; cf++){
    int d = cf * 16 + rl;
    float bpd = bp[d];
    for(int r = 0; r < 4; r++){
      int tl = w * 16 + kg * 4 + r;
      out[(size_t)(g0 + tl) * 256 + d] = acc[cf][r] + bpd;
    }
  }
}

extern "C" void kernel_launch(void* const* d_in, const int* in_sizes, int n_in,
                              void* d_out, int out_size, void* d_ws, size_t ws_size,
                              hipStream_t stream)
{
  const float* x  = (const float*)d_in[0];
  const float* ab = (const float*)d_in[1];
  const float* Wq = (const float*)d_in[2];
  const float* bq = (const float*)d_in[3];
  const float* Wk = (const float*)d_in[4];
  const float* bk = (const float*)d_in[5];
  const float* Wv = (const float*)d_in[6];
  const float* bv = (const float*)d_in[7];
  const float* Wp = (const float*)d_in[8];
  const float* bp = (const float*)d_in[9];
  float* out = (float*)d_out;

  char* ws = (char*)d_ws;
  float* Qsig          = (float*)(ws);                    // 8.4 MB
  float* Kt            = (float*)(ws + 8388608);          // 8.4 MB
  float* Vt            = (float*)(ws + 16777216);         // 8.4 MB
  unsigned short* Mt   = (unsigned short*)(ws + 25165824);// 8.4 MB bf16
  float* stats         = (float*)(ws + 33554432);         // 128 KB
  unsigned short* Yt   = (unsigned short*)(ws + 33685504);// 4.2 MB bf16

  qkv_kernel<<<dim3(256, 3), 256, 0, stream>>>(x, Wq, bq, Wk, bk, Wv, bv, Qsig, Kt, Vt);
  colsm_kernel<<<256, 256, 0, stream>>>(Kt, Vt, Mt);
  rowstats_kernel<<<16384, 256, 0, stream>>>(ab, stats);
  aft_gemm<<<256, 512, 0, stream>>>(ab, stats, Mt, Qsig, Yt);
  outproj_kernel<<<256, 256, 0, stream>>>(Yt, Wp, bp, out);
}

// Round 3
// 105.574 us; speedup vs baseline: 1.3650x; 1.3650x over previous
//
#include <hip/hip_runtime.h>
#include <hip/hip_bf16.h>

#define B_ 8
#define T_ 2048
#define D_ 256
#define H_ 128

typedef float f32x4 __attribute__((ext_vector_type(4)));
typedef short bf16x8 __attribute__((ext_vector_type(8)));

__device__ __forceinline__ unsigned short f2bf(float f){
  union { float f; unsigned u; } v; v.f = f;
  unsigned u = v.u;
  unsigned r = (u + 0x7FFFu + ((u >> 16) & 1u)) >> 16;
  return (unsigned short)r;
}

#define GLL16(g, l) __builtin_amdgcn_global_load_lds( \
    (const __attribute__((address_space(1))) void*)(g), \
    (__attribute__((address_space(3))) void*)(l), 16, 0, 0)

// 256-thread (4-wave) block reduce; sbuf must be float[4]
__device__ __forceinline__ float blk_reduce(float v, bool is_max, float* sbuf){
  for(int o = 32; o > 0; o >>= 1){
    float t = __shfl_xor(v, o);
    v = is_max ? fmaxf(v, t) : (v + t);
  }
  int w = threadIdx.x >> 6;
  __syncthreads();
  if((threadIdx.x & 63) == 0) sbuf[w] = v;
  __syncthreads();
  float r = sbuf[0];
  for(int i = 1; i < 4; i++) r = is_max ? fmaxf(r, sbuf[i]) : (r + sbuf[i]);
  return r;
}

// ---------------------------------------------------------------------------
// Kernel 1: QKV projection. grid (256 rowtiles, 3 mats), 256 threads.
// ---------------------------------------------------------------------------
__global__ __launch_bounds__(256) void qkv_kernel(
    const float* __restrict__ x,
    const float* __restrict__ Wq, const float* __restrict__ bq,
    const float* __restrict__ Wk, const float* __restrict__ bk,
    const float* __restrict__ Wv, const float* __restrict__ bv,
    float* __restrict__ Qsig, float* __restrict__ Kt, float* __restrict__ Vt)
{
  const int mat = blockIdx.y;
  const int g0  = blockIdx.x * 64;
  const int tid = threadIdx.x;
  const float* W   = (mat == 0) ? Wq : (mat == 1) ? Wk : Wv;
  const float* bia = (mat == 0) ? bq : (mat == 1) ? bk : bv;

  __shared__ __align__(16) short As[64 * 32];
  __shared__ __align__(16) short Ws[128 * 32];
  __shared__ float tbuf[64][129];

  const int w = tid >> 6, lane = tid & 63, rl = lane & 15, kg = lane >> 4;
  f32x4 acc[8];
  for(int i = 0; i < 8; i++) acc[i] = (f32x4){0.f, 0.f, 0.f, 0.f};

  const int c = tid & 31, r8 = tid >> 5;
  for(int kk = 0; kk < 256; kk += 32){
    __syncthreads();
    for(int p = 0; p < 8; p++){
      int rr = r8 + p * 8;
      As[rr * 32 + c] = (short)f2bf(x[(size_t)(g0 + rr) * 256 + kk + c]);
    }
    for(int p = 0; p < 16; p++){
      int hh = r8 + p * 8;
      Ws[hh * 32 + c] = (short)f2bf(W[(size_t)hh * 256 + kk + c]);
    }
    __syncthreads();
    bf16x8 a = *(const bf16x8*)&As[(w * 16 + rl) * 32 + kg * 8];
    for(int cf = 0; cf < 8; cf++){
      bf16x8 bb = *(const bf16x8*)&Ws[(cf * 16 + rl) * 32 + kg * 8];
      acc[cf] = __builtin_amdgcn_mfma_f32_16x16x32_bf16(a, bb, acc[cf], 0, 0, 0);
    }
  }

  const int b = g0 >> 11, t0 = g0 & 2047;
  if(mat == 0){
    for(int cf = 0; cf < 8; cf++){
      int h = cf * 16 + rl;
      float bh = bia[h];
      for(int r = 0; r < 4; r++){
        int tl = w * 16 + kg * 4 + r;
        float v = acc[cf][r] + bh;
        Qsig[(size_t)(g0 + tl) * 128 + h] = 1.f / (1.f + __expf(-v));
      }
    }
  } else {
    for(int cf = 0; cf < 8; cf++){
      int h = cf * 16 + rl;
      float bh = bia[h];
      for(int r = 0; r < 4; r++){
        int tl = w * 16 + kg * 4 + r;
        tbuf[tl][h] = acc[cf][r] + bh;
      }
    }
    __syncthreads();
    float* dst = (mat == 1) ? Kt : Vt;
    int h = tid >> 1, part = tid & 1;
    float* drow = dst + (size_t)(b * 128 + h) * 2048 + t0 + part * 32;
    for(int i = 0; i < 32; i += 4){
      float4 o;
      o.x = tbuf[part * 32 + i + 0][h];
      o.y = tbuf[part * 32 + i + 1][h];
      o.z = tbuf[part * 32 + i + 2][h];
      o.w = tbuf[part * 32 + i + 3][h];
      *(float4*)(drow + i) = o;
    }
  }
}

// ---------------------------------------------------------------------------
// Kernel 2: column softmax over time for K -> Mt rows 0..127 = bf16(eK*V),
// rows 128..255 = bf16(eK).
// ---------------------------------------------------------------------------
__global__ __launch_bounds__(256) void colsm_kernel(
    const float* __restrict__ Kt, const float* __restrict__ Vt,
    unsigned short* __restrict__ Mt)
{
  __shared__ float sbuf[4];
  const int b  = blockIdx.x >> 5;
  const int hg = blockIdx.x & 31;
  const int tid = threadIdx.x;
  for(int i = 0; i < 4; i++){
    int h = hg * 4 + i;
    const float* kr = Kt + (size_t)(b * 128 + h) * 2048;
    const float* vr = Vt + (size_t)(b * 128 + h) * 2048;
    float4 k0 = *(const float4*)(kr + tid * 4);
    float4 k1 = *(const float4*)(kr + tid * 4 + 1024);
    float m = fmaxf(fmaxf(fmaxf(k0.x, k0.y), fmaxf(k0.z, k0.w)),
                    fmaxf(fmaxf(k1.x, k1.y), fmaxf(k1.z, k1.w)));
    m = blk_reduce(m, true, sbuf);
    float s = __expf(k0.x - m) + __expf(k0.y - m) + __expf(k0.z - m) + __expf(k0.w - m)
            + __expf(k1.x - m) + __expf(k1.y - m) + __expf(k1.z - m) + __expf(k1.w - m);
    s = blk_reduce(s, false, sbuf);
    float iz = 1.f / s;
    float4 v0 = *(const float4*)(vr + tid * 4);
    float4 v1 = *(const float4*)(vr + tid * 4 + 1024);
    unsigned short* ekvp = Mt + (size_t)(b * 256 + h) * 2048;
    unsigned short* ekp  = Mt + (size_t)(b * 256 + 128 + h) * 2048;
    ushort4 pv, pe;
    float e;
    e = __expf(__expf(k0.x - m) * iz); pv.x = f2bf(e * v0.x); pe.x = f2bf(e);
    e = __expf(__expf(k0.y - m) * iz); pv.y = f2bf(e * v0.y); pe.y = f2bf(e);
    e = __expf(__expf(k0.z - m) * iz); pv.z = f2bf(e * v0.z); pe.z = f2bf(e);
    e = __expf(__expf(k0.w - m) * iz); pv.w = f2bf(e * v0.w); pe.w = f2bf(e);
    ((ushort4*)ekvp)[tid] = pv;
    ((ushort4*)ekp)[tid]  = pe;
    e = __expf(__expf(k1.x - m) * iz); pv.x = f2bf(e * v1.x); pe.x = f2bf(e);
    e = __expf(__expf(k1.y - m) * iz); pv.y = f2bf(e * v1.y); pe.y = f2bf(e);
    e = __expf(__expf(k1.z - m) * iz); pv.z = f2bf(e * v1.z); pe.z = f2bf(e);
    e = __expf(__expf(k1.w - m) * iz); pv.w = f2bf(e * v1.w); pe.w = f2bf(e);
    ((ushort4*)ekvp)[tid + 256] = pv;
    ((ushort4*)ekp)[tid + 256]  = pe;
  }
}

// ---------------------------------------------------------------------------
// Kernel 3: fused row-softmax + exp -> bf16 eab. One row per block, row held
// in registers (8 f32/thread). Reads ab once (134 MB), writes eab (67 MB).
// ---------------------------------------------------------------------------
__global__ __launch_bounds__(256) void softexp_kernel(
    const float* __restrict__ ab, unsigned short* __restrict__ eab)
{
  __shared__ float sbuf[4];
  const size_t row = blockIdx.x;
  const float* r = ab + row * 2048;
  const int tid = threadIdx.x;
  float4 v0 = *(const float4*)(r + tid * 4);
  float4 v1 = *(const float4*)(r + tid * 4 + 1024);
  float m = fmaxf(fmaxf(fmaxf(v0.x, v0.y), fmaxf(v0.z, v0.w)),
                  fmaxf(fmaxf(v1.x, v1.y), fmaxf(v1.z, v1.w)));
  m = blk_reduce(m, true, sbuf);
  float e0x = __expf(v0.x - m), e0y = __expf(v0.y - m);
  float e0z = __expf(v0.z - m), e0w = __expf(v0.w - m);
  float e1x = __expf(v1.x - m), e1y = __expf(v1.y - m);
  float e1z = __expf(v1.z - m), e1w = __expf(v1.w - m);
  float s = e0x + e0y + e0z + e0w + e1x + e1y + e1z + e1w;
  s = blk_reduce(s, false, sbuf);
  float iz = 1.f / s;
  ushort4 o;
  o.x = f2bf(__expf(e0x * iz)); o.y = f2bf(__expf(e0y * iz));
  o.z = f2bf(__expf(e0z * iz)); o.w = f2bf(__expf(e0w * iz));
  *(ushort4*)(eab + row * 2048 + tid * 4) = o;
  o.x = f2bf(__expf(e1x * iz)); o.y = f2bf(__expf(e1y * iz));
  o.z = f2bf(__expf(e1z * iz)); o.w = f2bf(__expf(e1w * iz));
  *(ushort4*)(eab + row * 2048 + tid * 4 + 1024) = o;
}

// ---------------------------------------------------------------------------
// Kernel 4: pure bf16 GEMM. C[32 x 256] = eab[32 x 2048] @ Mt[b]^T[2048 x 256]
// 2-phase pipeline, global_load_lds both operands, XOR-swizzled LDS,
// double-buffered, one barrier per K-step. grid 512 (XCD-bijective swizzle),
// 256 threads (4 waves; wave w owns cols [w*32, w*32+32) paired with +128).
// Epilogue: Yt = sigmoid(Q) * num/den -> bf16.
// ---------------------------------------------------------------------------
__global__ __launch_bounds__(256) void aft_gemm2(
    const unsigned short* __restrict__ eab,
    const unsigned short* __restrict__ Mt,
    const float* __restrict__ Qsig,
    unsigned short* __restrict__ Yt)
{
  __shared__ __align__(16) unsigned short As2[2][32 * 64];
  __shared__ __align__(16) unsigned short Bs2[2][256 * 64];

  const int bid = blockIdx.x;
  const int swz = (bid & 7) * 64 + (bid >> 3);   // 512 = 8 XCD * 64
  const int b   = swz >> 6;
  const int t0  = (swz & 63) * 32;

  const int tid = threadIdx.x;
  const int w = tid >> 6, lane = tid & 63;
  const int rl = lane & 15, kg = lane >> 4;

  // staging geometry: lane -> (row-in-8-group, chunk); source chunk inverse-swizzled
  const int lr = lane >> 3;
  const int cc = (lane & 7) ^ lr;     // rule #21: pre-swizzled global source

  const size_t rowbase = (size_t)b * 2048 + t0;
  const unsigned short* a_src = eab + (rowbase + (size_t)(w * 8 + lr)) * 2048 + cc * 8;
  const unsigned short* b_src = Mt + ((size_t)b * 256 + w * 64 + lr) * 2048 + cc * 8;

  f32x4 acc[2][4];
#pragma unroll
  for(int i = 0; i < 2; i++)
#pragma unroll
    for(int j = 0; j < 4; j++) acc[i][j] = (f32x4){0.f, 0.f, 0.f, 0.f};

  auto stage = [&](int buf, int t){
    GLL16(a_src + t * 64, &As2[buf][w * 512]);
#pragma unroll
    for(int i = 0; i < 8; i++)
      GLL16(b_src + i * 16384 + t * 64, &Bs2[buf][w * 4096 + i * 512]);
  };

  const int rx = rl & 7;
  stage(0, 0);
  __syncthreads();   // compiler drains vmcnt(0) before s_barrier

  for(int t = 0; t < 32; ++t){
    const int cur = t & 1;
    if(t < 31) stage(cur ^ 1, t + 1);   // prefetch overlaps compute
#pragma unroll
    for(int ks = 0; ks < 2; ++ks){
      const int slot = ((ks * 4 + kg) ^ rx) * 8;
      bf16x8 a0 = *(const bf16x8*)&As2[cur][rl * 64 + slot];
      bf16x8 a1 = *(const bf16x8*)&As2[cur][(16 + rl) * 64 + slot];
#pragma unroll
      for(int cf = 0; cf < 4; ++cf){
        const int crow = ((cf < 2) ? (w * 32 + cf * 16)
                                   : (128 + w * 32 + (cf - 2) * 16)) + rl;
        bf16x8 bb = *(const bf16x8*)&Bs2[cur][crow * 64 + slot];
        acc[0][cf] = __builtin_amdgcn_mfma_f32_16x16x32_bf16(a0, bb, acc[0][cf], 0, 0, 0);
        acc[1][cf] = __builtin_amdgcn_mfma_f32_16x16x32_bf16(a1, bb, acc[1][cf], 0, 0, 0);
      }
    }
    __syncthreads();
  }

#pragma unroll
  for(int rf = 0; rf < 2; ++rf)
#pragma unroll
    for(int cf = 0; cf < 2; ++cf){
      const int h = w * 32 + cf * 16 + rl;
#pragma unroll
      for(int r = 0; r < 4; ++r){
        const int tl = rf * 16 + kg * 4 + r;
        const size_t g = rowbase + tl;
        float num = acc[rf][cf][r], den = acc[rf][cf + 2][r];
        float q = Qsig[g * 128 + h];
        Yt[g * 128 + h] = f2bf(q * num / den);
      }
    }
}

// ---------------------------------------------------------------------------
// Kernel 5: output projection out = Yt @ Wp^T + bp. grid = 256, 256 threads.
// ---------------------------------------------------------------------------
__global__ __launch_bounds__(256) void outproj_kernel(
    const unsigned short* __restrict__ Yt, const float* __restrict__ Wp,
    const float* __restrict__ bp, float* __restrict__ out)
{
  __shared__ __align__(16) short As[64 * 32];
  __shared__ __align__(16) short Bs[256 * 32];
  const int g0 = blockIdx.x * 64;
  const int tid = threadIdx.x;
  const int w = tid >> 6, lane = tid & 63, rl = lane & 15, kg = lane >> 4;
  f32x4 acc[16];
  for(int i = 0; i < 16; i++) acc[i] = (f32x4){0.f, 0.f, 0.f, 0.f};

  const int ar = tid >> 2, apart = tid & 3;
  const int c = tid & 31, dr = tid >> 5;
  for(int k = 0; k < 128; k += 32){
    __syncthreads();
    *(uint4*)&As[ar * 32 + apart * 8] =
        *(const uint4*)(Yt + (size_t)(g0 + ar) * 128 + k + apart * 8);
    for(int p = 0; p < 32; p++){
      int d = dr + p * 8;
      Bs[d * 32 + c] = (short)f2bf(Wp[(size_t)d * 128 + k + c]);
    }
    __syncthreads();
    bf16x8 a = *(const bf16x8*)&As[(w * 16 + rl) * 32 + kg * 8];
    for(int cf = 0; cf < 16; cf++){
      bf16x8 bb = *(const bf16x8*)&Bs[(cf * 16 + rl) * 32 + kg * 8];
      acc[cf] = __builtin_amdgcn_mfma_f32_16x16x32_bf16(a, bb, acc[cf], 0, 0, 0);
    }
  }
  for(int cf = 0; cf < 16; cf++){
    int d = cf * 16 + rl;
    float bpd = bp[d];
    for(int r = 0; r < 4; r++){
      int tl = w * 16 + kg * 4 + r;
      out[(size_t)(g0 + tl) * 256 + d] = acc[cf][r] + bpd;
    }
  }
}

extern "C" void kernel_launch(void* const* d_in, const int* in_sizes, int n_in,
                              void* d_out, int out_size, void* d_ws, size_t ws_size,
                              hipStream_t stream)
{
  const float* x  = (const float*)d_in[0];
  const float* ab = (const float*)d_in[1];
  const float* Wq = (const float*)d_in[2];
  const float* bq = (const float*)d_in[3];
  const float* Wk = (const float*)d_in[4];
  const float* bk = (const float*)d_in[5];
  const float* Wv = (const float*)d_in[6];
  const float* bv = (const float*)d_in[7];
  const float* Wp = (const float*)d_in[8];
  const float* bp = (const float*)d_in[9];
  float* out = (float*)d_out;

  char* ws = (char*)d_ws;
  float* Qsig          = (float*)(ws);                     //  0.0 MB (8.4)
  float* Kt            = (float*)(ws + 8388608);           //  8.4 MB (8.4) -> Yt after colsm
  float* Vt            = (float*)(ws + 16777216);          // 16.8 MB (8.4)
  unsigned short* Mt   = (unsigned short*)(ws + 25165824); // 25.2 MB (8.4)
  unsigned short* eab  = (unsigned short*)(ws + 33554432); // 33.6 MB (67.1)
  unsigned short* Yt   = (unsigned short*)(ws + 8388608);  // reuse Kt slot (4.2)

  qkv_kernel<<<dim3(256, 3), 256, 0, stream>>>(x, Wq, bq, Wk, bk, Wv, bv, Qsig, Kt, Vt);
  colsm_kernel<<<256, 256, 0, stream>>>(Kt, Vt, Mt);
  softexp_kernel<<<16384, 256, 0, stream>>>(ab, eab);
  aft_gemm2<<<512, 256, 0, stream>>>(eab, Mt, Qsig, Yt);
  outproj_kernel<<<256, 256, 0, stream>>>(Yt, Wp, bp, out);
}

// Round 4
// 103.229 us; speedup vs baseline: 1.3961x; 1.0227x over previous
//
#include <hip/hip_runtime.h>
#include <hip/hip_bf16.h>

#define B_ 8
#define T_ 2048
#define D_ 256
#define H_ 128

typedef float f32x4 __attribute__((ext_vector_type(4)));
typedef short bf16x8 __attribute__((ext_vector_type(8)));

__device__ __forceinline__ unsigned short f2bf(float f){
  union { float f; unsigned u; } v; v.f = f;
  unsigned u = v.u;
  unsigned r = (u + 0x7FFFu + ((u >> 16) & 1u)) >> 16;
  return (unsigned short)r;
}

#define GLL16(g, l) __builtin_amdgcn_global_load_lds( \
    (const __attribute__((address_space(1))) void*)(g), \
    (__attribute__((address_space(3))) void*)(l), 16, 0, 0)

// 256-thread (4-wave) block reduce; sbuf must be float[4]
__device__ __forceinline__ float blk_reduce(float v, bool is_max, float* sbuf){
  for(int o = 32; o > 0; o >>= 1){
    float t = __shfl_xor(v, o);
    v = is_max ? fmaxf(v, t) : (v + t);
  }
  int w = threadIdx.x >> 6;
  __syncthreads();
  if((threadIdx.x & 63) == 0) sbuf[w] = v;
  __syncthreads();
  float r = sbuf[0];
  for(int i = 1; i < 4; i++) r = is_max ? fmaxf(r, sbuf[i]) : (r + sbuf[i]);
  return r;
}

// ---------------------------------------------------------------------------
// Kernel 1: QKV projection. grid (256 rowtiles, 3 mats), 256 threads.
// ---------------------------------------------------------------------------
__global__ __launch_bounds__(256) void qkv_kernel(
    const float* __restrict__ x,
    const float* __restrict__ Wq, const float* __restrict__ bq,
    const float* __restrict__ Wk, const float* __restrict__ bk,
    const float* __restrict__ Wv, const float* __restrict__ bv,
    float* __restrict__ Qsig, float* __restrict__ Kt, float* __restrict__ Vt)
{
  const int mat = blockIdx.y;
  const int g0  = blockIdx.x * 64;
  const int tid = threadIdx.x;
  const float* W   = (mat == 0) ? Wq : (mat == 1) ? Wk : Wv;
  const float* bia = (mat == 0) ? bq : (mat == 1) ? bk : bv;

  __shared__ __align__(16) short As[64 * 32];
  __shared__ __align__(16) short Ws[128 * 32];
  __shared__ float tbuf[64][129];

  const int w = tid >> 6, lane = tid & 63, rl = lane & 15, kg = lane >> 4;
  f32x4 acc[8];
  for(int i = 0; i < 8; i++) acc[i] = (f32x4){0.f, 0.f, 0.f, 0.f};

  const int c = tid & 31, r8 = tid >> 5;
  for(int kk = 0; kk < 256; kk += 32){
    __syncthreads();
    for(int p = 0; p < 8; p++){
      int rr = r8 + p * 8;
      As[rr * 32 + c] = (short)f2bf(x[(size_t)(g0 + rr) * 256 + kk + c]);
    }
    for(int p = 0; p < 16; p++){
      int hh = r8 + p * 8;
      Ws[hh * 32 + c] = (short)f2bf(W[(size_t)hh * 256 + kk + c]);
    }
    __syncthreads();
    bf16x8 a = *(const bf16x8*)&As[(w * 16 + rl) * 32 + kg * 8];
    for(int cf = 0; cf < 8; cf++){
      bf16x8 bb = *(const bf16x8*)&Ws[(cf * 16 + rl) * 32 + kg * 8];
      acc[cf] = __builtin_amdgcn_mfma_f32_16x16x32_bf16(a, bb, acc[cf], 0, 0, 0);
    }
  }

  const int b = g0 >> 11, t0 = g0 & 2047;
  if(mat == 0){
    for(int cf = 0; cf < 8; cf++){
      int h = cf * 16 + rl;
      float bh = bia[h];
      for(int r = 0; r < 4; r++){
        int tl = w * 16 + kg * 4 + r;
        float v = acc[cf][r] + bh;
        Qsig[(size_t)(g0 + tl) * 128 + h] = 1.f / (1.f + __expf(-v));
      }
    }
  } else {
    for(int cf = 0; cf < 8; cf++){
      int h = cf * 16 + rl;
      float bh = bia[h];
      for(int r = 0; r < 4; r++){
        int tl = w * 16 + kg * 4 + r;
        tbuf[tl][h] = acc[cf][r] + bh;
      }
    }
    __syncthreads();
    float* dst = (mat == 1) ? Kt : Vt;
    int h = tid >> 1, part = tid & 1;
    float* drow = dst + (size_t)(b * 128 + h) * 2048 + t0 + part * 32;
    for(int i = 0; i < 32; i += 4){
      float4 o;
      o.x = tbuf[part * 32 + i + 0][h];
      o.y = tbuf[part * 32 + i + 1][h];
      o.z = tbuf[part * 32 + i + 2][h];
      o.w = tbuf[part * 32 + i + 3][h];
      *(float4*)(drow + i) = o;
    }
  }
}

// ---------------------------------------------------------------------------
// Kernel 2: column softmax over time for K -> Mt rows 0..127 = bf16(eK*V),
// rows 128..255 = bf16(eK).
// ---------------------------------------------------------------------------
__global__ __launch_bounds__(256) void colsm_kernel(
    const float* __restrict__ Kt, const float* __restrict__ Vt,
    unsigned short* __restrict__ Mt)
{
  __shared__ float sbuf[4];
  const int b  = blockIdx.x >> 5;
  const int hg = blockIdx.x & 31;
  const int tid = threadIdx.x;
  for(int i = 0; i < 4; i++){
    int h = hg * 4 + i;
    const float* kr = Kt + (size_t)(b * 128 + h) * 2048;
    const float* vr = Vt + (size_t)(b * 128 + h) * 2048;
    float4 k0 = *(const float4*)(kr + tid * 4);
    float4 k1 = *(const float4*)(kr + tid * 4 + 1024);
    float m = fmaxf(fmaxf(fmaxf(k0.x, k0.y), fmaxf(k0.z, k0.w)),
                    fmaxf(fmaxf(k1.x, k1.y), fmaxf(k1.z, k1.w)));
    m = blk_reduce(m, true, sbuf);
    float s = __expf(k0.x - m) + __expf(k0.y - m) + __expf(k0.z - m) + __expf(k0.w - m)
            + __expf(k1.x - m) + __expf(k1.y - m) + __expf(k1.z - m) + __expf(k1.w - m);
    s = blk_reduce(s, false, sbuf);
    float iz = 1.f / s;
    float4 v0 = *(const float4*)(vr + tid * 4);
    float4 v1 = *(const float4*)(vr + tid * 4 + 1024);
    unsigned short* ekvp = Mt + (size_t)(b * 256 + h) * 2048;
    unsigned short* ekp  = Mt + (size_t)(b * 256 + 128 + h) * 2048;
    ushort4 pv, pe;
    float e;
    e = __expf(__expf(k0.x - m) * iz); pv.x = f2bf(e * v0.x); pe.x = f2bf(e);
    e = __expf(__expf(k0.y - m) * iz); pv.y = f2bf(e * v0.y); pe.y = f2bf(e);
    e = __expf(__expf(k0.z - m) * iz); pv.z = f2bf(e * v0.z); pe.z = f2bf(e);
    e = __expf(__expf(k0.w - m) * iz); pv.w = f2bf(e * v0.w); pe.w = f2bf(e);
    ((ushort4*)ekvp)[tid] = pv;
    ((ushort4*)ekp)[tid]  = pe;
    e = __expf(__expf(k1.x - m) * iz); pv.x = f2bf(e * v1.x); pe.x = f2bf(e);
    e = __expf(__expf(k1.y - m) * iz); pv.y = f2bf(e * v1.y); pe.y = f2bf(e);
    e = __expf(__expf(k1.z - m) * iz); pv.z = f2bf(e * v1.z); pe.z = f2bf(e);
    e = __expf(__expf(k1.w - m) * iz); pv.w = f2bf(e * v1.w); pe.w = f2bf(e);
    ((ushort4*)ekvp)[tid + 256] = pv;
    ((ushort4*)ekp)[tid + 256]  = pe;
  }
}

// ---------------------------------------------------------------------------
// Kernel 3: fused row-softmax + exp -> bf16 eab. One row per block.
// ---------------------------------------------------------------------------
__global__ __launch_bounds__(256) void softexp_kernel(
    const float* __restrict__ ab, unsigned short* __restrict__ eab)
{
  __shared__ float sbuf[4];
  const size_t row = blockIdx.x;
  const float* r = ab + row * 2048;
  const int tid = threadIdx.x;
  float4 v0 = *(const float4*)(r + tid * 4);
  float4 v1 = *(const float4*)(r + tid * 4 + 1024);
  float m = fmaxf(fmaxf(fmaxf(v0.x, v0.y), fmaxf(v0.z, v0.w)),
                  fmaxf(fmaxf(v1.x, v1.y), fmaxf(v1.z, v1.w)));
  m = blk_reduce(m, true, sbuf);
  float e0x = __expf(v0.x - m), e0y = __expf(v0.y - m);
  float e0z = __expf(v0.z - m), e0w = __expf(v0.w - m);
  float e1x = __expf(v1.x - m), e1y = __expf(v1.y - m);
  float e1z = __expf(v1.z - m), e1w = __expf(v1.w - m);
  float s = e0x + e0y + e0z + e0w + e1x + e1y + e1z + e1w;
  s = blk_reduce(s, false, sbuf);
  float iz = 1.f / s;
  ushort4 o;
  o.x = f2bf(__expf(e0x * iz)); o.y = f2bf(__expf(e0y * iz));
  o.z = f2bf(__expf(e0z * iz)); o.w = f2bf(__expf(e0w * iz));
  *(ushort4*)(eab + row * 2048 + tid * 4) = o;
  o.x = f2bf(__expf(e1x * iz)); o.y = f2bf(__expf(e1y * iz));
  o.z = f2bf(__expf(e1z * iz)); o.w = f2bf(__expf(e1w * iz));
  *(ushort4*)(eab + row * 2048 + tid * 4 + 1024) = o;
}

// ---------------------------------------------------------------------------
// Kernel 4: pure bf16 GEMM, rebalanced tile.
// Block tile: 64 rows x (64 num cols + 64 den cols), BK=64, 4 waves.
// grid 512 = 8 XCD * 64; bid&7 = batch (Mt[b] L2-resident per XCD).
// LDS 48 KB -> 2 blocks/CU. Per wave/K-step: 16 MFMA vs 6 global_load_lds.
// Epilogue: Yt = sigmoid(Q) * num/den -> bf16.
// ---------------------------------------------------------------------------
__global__ __launch_bounds__(256) void aft_gemm3(
    const unsigned short* __restrict__ eab,
    const unsigned short* __restrict__ Mt,
    const float* __restrict__ Qsig,
    unsigned short* __restrict__ Yt)
{
  __shared__ __align__(16) unsigned short As2[2][64 * 64];   // 16 KB
  __shared__ __align__(16) unsigned short Bs2[2][128 * 64];  // 32 KB

  const int bid = blockIdx.x;
  const int b   = bid & 7;
  const int idx = bid >> 3;          // 0..63
  const int rt  = idx >> 1;          // 0..31
  const int hb  = idx & 1;           // 0..1
  const int t0  = rt * 64;
  const int h0  = hb * 64;

  const int tid = threadIdx.x;
  const int w = tid >> 6, lane = tid & 63;
  const int rl = lane & 15, kg = lane >> 4;
  const int wr = w >> 1, wc = w & 1;

  // staging geometry (rule #21: linear LDS dest, inverse-swizzled global src)
  const int lr = lane >> 3;          // 0..7
  const int cc = (lane & 7) ^ lr;    // chunk of 8 shorts

  const size_t rowbase = (size_t)b * 2048 + t0;
  const unsigned short* a_src = eab + (rowbase + (size_t)(w * 16 + lr)) * 2048 + cc * 8;
  const int mtrow = (w < 2) ? (h0 + w * 32 + lr) : (128 + h0 + (w - 2) * 32 + lr);
  const unsigned short* b_src = Mt + ((size_t)b * 256 + mtrow) * 2048 + cc * 8;

  f32x4 acc[2][4];
#pragma unroll
  for(int i = 0; i < 2; i++)
#pragma unroll
    for(int j = 0; j < 4; j++) acc[i][j] = (f32x4){0.f, 0.f, 0.f, 0.f};

  auto stage = [&](int buf, int t){
#pragma unroll
    for(int i = 0; i < 2; i++)
      GLL16(a_src + (size_t)i * 8 * 2048 + t * 64, &As2[buf][(w * 16 + i * 8) * 64]);
#pragma unroll
    for(int i = 0; i < 4; i++)
      GLL16(b_src + (size_t)i * 8 * 2048 + t * 64, &Bs2[buf][(w * 32 + i * 8) * 64]);
  };

  const int rx = rl & 7;
  stage(0, 0);
  __syncthreads();

  for(int t = 0; t < 32; ++t){
    const int cur = t & 1;
    if(t < 31) stage(cur ^ 1, t + 1);   // prefetch overlaps compute
#pragma unroll
    for(int ks = 0; ks < 2; ++ks){
      const int slot = ((ks * 4 + kg) ^ rx) * 8;
      bf16x8 a0 = *(const bf16x8*)&As2[cur][(wr * 32 + rl) * 64 + slot];
      bf16x8 a1 = *(const bf16x8*)&As2[cur][(wr * 32 + 16 + rl) * 64 + slot];
#pragma unroll
      for(int cf = 0; cf < 4; ++cf){
        const int brow = ((cf < 2) ? (wc * 32 + cf * 16)
                                   : (64 + wc * 32 + (cf - 2) * 16)) + rl;
        bf16x8 bb = *(const bf16x8*)&Bs2[cur][brow * 64 + slot];
        acc[0][cf] = __builtin_amdgcn_mfma_f32_16x16x32_bf16(a0, bb, acc[0][cf], 0, 0, 0);
        acc[1][cf] = __builtin_amdgcn_mfma_f32_16x16x32_bf16(a1, bb, acc[1][cf], 0, 0, 0);
      }
    }
    __syncthreads();
  }

#pragma unroll
  for(int rf = 0; rf < 2; ++rf)
#pragma unroll
    for(int cf = 0; cf < 2; ++cf){
      const int h = h0 + wc * 32 + cf * 16 + rl;
#pragma unroll
      for(int r = 0; r < 4; ++r){
        const int tl = wr * 32 + rf * 16 + kg * 4 + r;
        const size_t g = rowbase + tl;
        float num = acc[rf][cf][r], den = acc[rf][cf + 2][r];
        float q = Qsig[g * 128 + h];
        Yt[g * 128 + h] = f2bf(q * num / den);
      }
    }
}

// ---------------------------------------------------------------------------
// Kernel 5: output projection out = Yt @ Wp^T + bp. grid = 256, 256 threads.
// ---------------------------------------------------------------------------
__global__ __launch_bounds__(256) void outproj_kernel(
    const unsigned short* __restrict__ Yt, const float* __restrict__ Wp,
    const float* __restrict__ bp, float* __restrict__ out)
{
  __shared__ __align__(16) short As[64 * 32];
  __shared__ __align__(16) short Bs[256 * 32];
  const int g0 = blockIdx.x * 64;
  const int tid = threadIdx.x;
  const int w = tid >> 6, lane = tid & 63, rl = lane & 15, kg = lane >> 4;
  f32x4 acc[16];
  for(int i = 0; i < 16; i++) acc[i] = (f32x4){0.f, 0.f, 0.f, 0.f};

  const int ar = tid >> 2, apart = tid & 3;
  const int c = tid & 31, dr = tid >> 5;
  for(int k = 0; k < 128; k += 32){
    __syncthreads();
    *(uint4*)&As[ar * 32 + apart * 8] =
        *(const uint4*)(Yt + (size_t)(g0 + ar) * 128 + k + apart * 8);
    for(int p = 0; p < 32; p++){
      int d = dr + p * 8;
      Bs[d * 32 + c] = (short)f2bf(Wp[(size_t)d * 128 + k + c]);
    }
    __syncthreads();
    bf16x8 a = *(const bf16x8*)&As[(w * 16 + rl) * 32 + kg * 8];
    for(int cf = 0; cf < 16; cf++){
      bf16x8 bb = *(const bf16x8*)&Bs[(cf * 16 + rl) * 32 + kg * 8];
      acc[cf] = __builtin_amdgcn_mfma_f32_16x16x32_bf16(a, bb, acc[cf], 0, 0, 0);
    }
  }
  for(int cf = 0; cf < 16; cf++){
    int d = cf * 16 + rl;
    float bpd = bp[d];
    for(int r = 0; r < 4; r++){
      int tl = w * 16 + kg * 4 + r;
      out[(size_t)(g0 + tl) * 256 + d] = acc[cf][r] + bpd;
    }
  }
}

extern "C" void kernel_launch(void* const* d_in, const int* in_sizes, int n_in,
                              void* d_out, int out_size, void* d_ws, size_t ws_size,
                              hipStream_t stream)
{
  const float* x  = (const float*)d_in[0];
  const float* ab = (const float*)d_in[1];
  const float* Wq = (const float*)d_in[2];
  const float* bq = (const float*)d_in[3];
  const float* Wk = (const float*)d_in[4];
  const float* bk = (const float*)d_in[5];
  const float* Wv = (const float*)d_in[6];
  const float* bv = (const float*)d_in[7];
  const float* Wp = (const float*)d_in[8];
  const float* bp = (const float*)d_in[9];
  float* out = (float*)d_out;

  char* ws = (char*)d_ws;
  float* Qsig          = (float*)(ws);                     //  0.0 MB (8.4)
  float* Kt            = (float*)(ws + 8388608);           //  8.4 MB (8.4) -> Yt after colsm
  float* Vt            = (float*)(ws + 16777216);          // 16.8 MB (8.4)
  unsigned short* Mt   = (unsigned short*)(ws + 25165824); // 25.2 MB (8.4)
  unsigned short* eab  = (unsigned short*)(ws + 33554432); // 33.6 MB (67.1)
  unsigned short* Yt   = (unsigned short*)(ws + 8388608);  // reuse Kt slot (4.2)

  qkv_kernel<<<dim3(256, 3), 256, 0, stream>>>(x, Wq, bq, Wk, bk, Wv, bv, Qsig, Kt, Vt);
  colsm_kernel<<<256, 256, 0, stream>>>(Kt, Vt, Mt);
  softexp_kernel<<<16384, 256, 0, stream>>>(ab, eab);
  aft_gemm3<<<512, 256, 0, stream>>>(eab, Mt, Qsig, Yt);
  outproj_kernel<<<256, 256, 0, stream>>>(Yt, Wp, bp, out);
}

// Round 5
// 96.506 us; speedup vs baseline: 1.4933x; 1.0697x over previous
//
#include <hip/hip_runtime.h>
#include <hip/hip_bf16.h>

#define B_ 8
#define T_ 2048
#define D_ 256
#define H_ 128

typedef float f32x4 __attribute__((ext_vector_type(4)));
typedef short bf16x8 __attribute__((ext_vector_type(8)));

__device__ __forceinline__ unsigned short f2bf(float f){
  union { float f; unsigned u; } v; v.f = f;
  unsigned u = v.u;
  unsigned r = (u + 0x7FFFu + ((u >> 16) & 1u)) >> 16;
  return (unsigned short)r;
}

#define GLL16(g, l) __builtin_amdgcn_global_load_lds( \
    (const __attribute__((address_space(1))) void*)(g), \
    (__attribute__((address_space(3))) void*)(l), 16, 0, 0)

// 256-thread (4-wave) block reduce; sbuf must be float[4]
__device__ __forceinline__ float blk_reduce(float v, bool is_max, float* sbuf){
  for(int o = 32; o > 0; o >>= 1){
    float t = __shfl_xor(v, o);
    v = is_max ? fmaxf(v, t) : (v + t);
  }
  int w = threadIdx.x >> 6;
  __syncthreads();
  if((threadIdx.x & 63) == 0) sbuf[w] = v;
  __syncthreads();
  float r = sbuf[0];
  for(int i = 1; i < 4; i++) r = is_max ? fmaxf(r, sbuf[i]) : (r + sbuf[i]);
  return r;
}

// ---------------------------------------------------------------------------
// Kernel 1: QKV projection. grid (256 rowtiles, 3 mats), 256 threads.
// ---------------------------------------------------------------------------
__global__ __launch_bounds__(256) void qkv_kernel(
    const float* __restrict__ x,
    const float* __restrict__ Wq, const float* __restrict__ bq,
    const float* __restrict__ Wk, const float* __restrict__ bk,
    const float* __restrict__ Wv, const float* __restrict__ bv,
    float* __restrict__ Qsig, float* __restrict__ Kt, float* __restrict__ Vt)
{
  const int mat = blockIdx.y;
  const int g0  = blockIdx.x * 64;
  const int tid = threadIdx.x;
  const float* W   = (mat == 0) ? Wq : (mat == 1) ? Wk : Wv;
  const float* bia = (mat == 0) ? bq : (mat == 1) ? bk : bv;

  __shared__ __align__(16) short As[64 * 32];
  __shared__ __align__(16) short Ws[128 * 32];
  __shared__ float tbuf[64][129];

  const int w = tid >> 6, lane = tid & 63, rl = lane & 15, kg = lane >> 4;
  f32x4 acc[8];
  for(int i = 0; i < 8; i++) acc[i] = (f32x4){0.f, 0.f, 0.f, 0.f};

  const int c = tid & 31, r8 = tid >> 5;
  for(int kk = 0; kk < 256; kk += 32){
    __syncthreads();
    for(int p = 0; p < 8; p++){
      int rr = r8 + p * 8;
      As[rr * 32 + c] = (short)f2bf(x[(size_t)(g0 + rr) * 256 + kk + c]);
    }
    for(int p = 0; p < 16; p++){
      int hh = r8 + p * 8;
      Ws[hh * 32 + c] = (short)f2bf(W[(size_t)hh * 256 + kk + c]);
    }
    __syncthreads();
    bf16x8 a = *(const bf16x8*)&As[(w * 16 + rl) * 32 + kg * 8];
    for(int cf = 0; cf < 8; cf++){
      bf16x8 bb = *(const bf16x8*)&Ws[(cf * 16 + rl) * 32 + kg * 8];
      acc[cf] = __builtin_amdgcn_mfma_f32_16x16x32_bf16(a, bb, acc[cf], 0, 0, 0);
    }
  }

  const int b = g0 >> 11, t0 = g0 & 2047;
  if(mat == 0){
    for(int cf = 0; cf < 8; cf++){
      int h = cf * 16 + rl;
      float bh = bia[h];
      for(int r = 0; r < 4; r++){
        int tl = w * 16 + kg * 4 + r;
        float v = acc[cf][r] + bh;
        Qsig[(size_t)(g0 + tl) * 128 + h] = 1.f / (1.f + __expf(-v));
      }
    }
  } else {
    for(int cf = 0; cf < 8; cf++){
      int h = cf * 16 + rl;
      float bh = bia[h];
      for(int r = 0; r < 4; r++){
        int tl = w * 16 + kg * 4 + r;
        tbuf[tl][h] = acc[cf][r] + bh;
      }
    }
    __syncthreads();
    float* dst = (mat == 1) ? Kt : Vt;
    int h = tid >> 1, part = tid & 1;
    float* drow = dst + (size_t)(b * 128 + h) * 2048 + t0 + part * 32;
    for(int i = 0; i < 32; i += 4){
      float4 o;
      o.x = tbuf[part * 32 + i + 0][h];
      o.y = tbuf[part * 32 + i + 1][h];
      o.z = tbuf[part * 32 + i + 2][h];
      o.w = tbuf[part * 32 + i + 3][h];
      *(float4*)(drow + i) = o;
    }
  }
}

// ---------------------------------------------------------------------------
// Kernel 2: column softmax over time for K -> Mt rows 0..127 = bf16(eK*V),
// rows 128..255 = bf16(eK).
// ---------------------------------------------------------------------------
__global__ __launch_bounds__(256) void colsm_kernel(
    const float* __restrict__ Kt, const float* __restrict__ Vt,
    unsigned short* __restrict__ Mt)
{
  __shared__ float sbuf[4];
  const int b  = blockIdx.x >> 5;
  const int hg = blockIdx.x & 31;
  const int tid = threadIdx.x;
  for(int i = 0; i < 4; i++){
    int h = hg * 4 + i;
    const float* kr = Kt + (size_t)(b * 128 + h) * 2048;
    const float* vr = Vt + (size_t)(b * 128 + h) * 2048;
    float4 k0 = *(const float4*)(kr + tid * 4);
    float4 k1 = *(const float4*)(kr + tid * 4 + 1024);
    float m = fmaxf(fmaxf(fmaxf(k0.x, k0.y), fmaxf(k0.z, k0.w)),
                    fmaxf(fmaxf(k1.x, k1.y), fmaxf(k1.z, k1.w)));
    m = blk_reduce(m, true, sbuf);
    float s = __expf(k0.x - m) + __expf(k0.y - m) + __expf(k0.z - m) + __expf(k0.w - m)
            + __expf(k1.x - m) + __expf(k1.y - m) + __expf(k1.z - m) + __expf(k1.w - m);
    s = blk_reduce(s, false, sbuf);
    float iz = 1.f / s;
    float4 v0 = *(const float4*)(vr + tid * 4);
    float4 v1 = *(const float4*)(vr + tid * 4 + 1024);
    unsigned short* ekvp = Mt + (size_t)(b * 256 + h) * 2048;
    unsigned short* ekp  = Mt + (size_t)(b * 256 + 128 + h) * 2048;
    ushort4 pv, pe;
    float e;
    e = __expf(__expf(k0.x - m) * iz); pv.x = f2bf(e * v0.x); pe.x = f2bf(e);
    e = __expf(__expf(k0.y - m) * iz); pv.y = f2bf(e * v0.y); pe.y = f2bf(e);
    e = __expf(__expf(k0.z - m) * iz); pv.z = f2bf(e * v0.z); pe.z = f2bf(e);
    e = __expf(__expf(k0.w - m) * iz); pv.w = f2bf(e * v0.w); pe.w = f2bf(e);
    ((ushort4*)ekvp)[tid] = pv;
    ((ushort4*)ekp)[tid]  = pe;
    e = __expf(__expf(k1.x - m) * iz); pv.x = f2bf(e * v1.x); pe.x = f2bf(e);
    e = __expf(__expf(k1.y - m) * iz); pv.y = f2bf(e * v1.y); pe.y = f2bf(e);
    e = __expf(__expf(k1.z - m) * iz); pv.z = f2bf(e * v1.z); pe.z = f2bf(e);
    e = __expf(__expf(k1.w - m) * iz); pv.w = f2bf(e * v1.w); pe.w = f2bf(e);
    ((ushort4*)ekvp)[tid + 256] = pv;
    ((ushort4*)ekp)[tid + 256]  = pe;
  }
}

// ---------------------------------------------------------------------------
// Kernel 3: fused row-softmax + exp -> bf16 eab. One row per block.
// ---------------------------------------------------------------------------
__global__ __launch_bounds__(256) void softexp_kernel(
    const float* __restrict__ ab, unsigned short* __restrict__ eab)
{
  __shared__ float sbuf[4];
  const size_t row = blockIdx.x;
  const float* r = ab + row * 2048;
  const int tid = threadIdx.x;
  float4 v0 = *(const float4*)(r + tid * 4);
  float4 v1 = *(const float4*)(r + tid * 4 + 1024);
  float m = fmaxf(fmaxf(fmaxf(v0.x, v0.y), fmaxf(v0.z, v0.w)),
                  fmaxf(fmaxf(v1.x, v1.y), fmaxf(v1.z, v1.w)));
  m = blk_reduce(m, true, sbuf);
  float e0x = __expf(v0.x - m), e0y = __expf(v0.y - m);
  float e0z = __expf(v0.z - m), e0w = __expf(v0.w - m);
  float e1x = __expf(v1.x - m), e1y = __expf(v1.y - m);
  float e1z = __expf(v1.z - m), e1w = __expf(v1.w - m);
  float s = e0x + e0y + e0z + e0w + e1x + e1y + e1z + e1w;
  s = blk_reduce(s, false, sbuf);
  float iz = 1.f / s;
  ushort4 o;
  o.x = f2bf(__expf(e0x * iz)); o.y = f2bf(__expf(e0y * iz));
  o.z = f2bf(__expf(e0z * iz)); o.w = f2bf(__expf(e0w * iz));
  *(ushort4*)(eab + row * 2048 + tid * 4) = o;
  o.x = f2bf(__expf(e1x * iz)); o.y = f2bf(__expf(e1y * iz));
  o.z = f2bf(__expf(e1z * iz)); o.w = f2bf(__expf(e1w * iz));
  *(ushort4*)(eab + row * 2048 + tid * 4 + 1024) = o;
}

// ---------------------------------------------------------------------------
// Kernel 4: pure bf16 GEMM, counted-vmcnt schedule (T4).
// Geometry identical to verified aft_gemm3: 64 rows x (64 num + 64 den cols),
// BK=64, 4 waves, grid 512 = 8 XCD * 64 (batch pinned to XCD).
// Schedule: 2 K-tiles in flight (12 loads/lane); per iter:
//   vmcnt(6) -> s_barrier -> ds_read 12 frags -> lgkmcnt(0) -> s_barrier
//   -> restage buf[cur] for t+2 -> setprio(1) 16 MFMA setprio(0).
// vmcnt never drains to 0 except the peeled final iteration.
// ---------------------------------------------------------------------------
__global__ __launch_bounds__(256) void aft_gemm4(
    const unsigned short* __restrict__ eab,
    const unsigned short* __restrict__ Mt,
    const float* __restrict__ Qsig,
    unsigned short* __restrict__ Yt)
{
  __shared__ __align__(16) unsigned short As2[2][64 * 64];   // 16 KB
  __shared__ __align__(16) unsigned short Bs2[2][128 * 64];  // 32 KB

  const int bid = blockIdx.x;
  const int b   = bid & 7;
  const int idx = bid >> 3;          // 0..63
  const int rt  = idx >> 1;          // 0..31
  const int hb  = idx & 1;           // 0..1
  const int t0  = rt * 64;
  const int h0  = hb * 64;

  const int tid = threadIdx.x;
  const int w = tid >> 6, lane = tid & 63;
  const int rl = lane & 15, kg = lane >> 4;
  const int wr = w >> 1, wc = w & 1;

  // staging geometry (rule #21: linear LDS dest, inverse-swizzled global src)
  const int lr = lane >> 3;          // 0..7
  const int cc = (lane & 7) ^ lr;    // chunk of 8 shorts

  const size_t rowbase = (size_t)b * 2048 + t0;
  const unsigned short* a_src = eab + (rowbase + (size_t)(w * 16 + lr)) * 2048 + cc * 8;
  const int mtrow = (w < 2) ? (h0 + w * 32 + lr) : (128 + h0 + (w - 2) * 32 + lr);
  const unsigned short* b_src = Mt + ((size_t)b * 256 + mtrow) * 2048 + cc * 8;

  f32x4 acc[2][4];
#pragma unroll
  for(int i = 0; i < 2; i++)
#pragma unroll
    for(int j = 0; j < 4; j++) acc[i][j] = (f32x4){0.f, 0.f, 0.f, 0.f};

  auto stage = [&](int buf, int t){
#pragma unroll
    for(int i = 0; i < 2; i++)
      GLL16(a_src + (size_t)i * 8 * 2048 + t * 64, &As2[buf][(w * 16 + i * 8) * 64]);
#pragma unroll
    for(int i = 0; i < 4; i++)
      GLL16(b_src + (size_t)i * 8 * 2048 + t * 64, &Bs2[buf][(w * 32 + i * 8) * 64]);
  };

  const int rx = rl & 7;
  stage(0, 0);
  stage(1, 1);                       // 12 loads/lane outstanding

  for(int t = 0; t < 32; ++t){
    const int cur = t & 1;
    if(t < 31) asm volatile("s_waitcnt vmcnt(6)" ::: "memory");  // stage(t) landed
    else       asm volatile("s_waitcnt vmcnt(0)" ::: "memory");  // final tile
    __builtin_amdgcn_s_barrier();     // buf[cur] visible to all waves
    asm volatile("" ::: "memory");

    // ds_read all 12 fragments of this K-tile into registers
    bf16x8 af[2][2], bf[2][4];
#pragma unroll
    for(int ks = 0; ks < 2; ++ks){
      const int slot = ((ks * 4 + kg) ^ rx) * 8;
      af[ks][0] = *(const bf16x8*)&As2[cur][(wr * 32 + rl) * 64 + slot];
      af[ks][1] = *(const bf16x8*)&As2[cur][(wr * 32 + 16 + rl) * 64 + slot];
#pragma unroll
      for(int cf = 0; cf < 4; ++cf){
        const int brow = ((cf < 2) ? (wc * 32 + cf * 16)
                                   : (64 + wc * 32 + (cf - 2) * 16)) + rl;
        bf[ks][cf] = *(const bf16x8*)&Bs2[cur][brow * 64 + slot];
      }
    }
    asm volatile("s_waitcnt lgkmcnt(0)" ::: "memory");
    __builtin_amdgcn_sched_barrier(0);   // rule #18: pin MFMA below the wait
    __builtin_amdgcn_s_barrier();        // all waves done READING buf[cur]
    asm volatile("" ::: "memory");

    if(t < 30) stage(cur, t + 2);        // refill the buffer we just consumed

    __builtin_amdgcn_s_setprio(1);
#pragma unroll
    for(int ks = 0; ks < 2; ++ks)
#pragma unroll
      for(int cf = 0; cf < 4; ++cf){
        acc[0][cf] = __builtin_amdgcn_mfma_f32_16x16x32_bf16(af[ks][0], bf[ks][cf], acc[0][cf], 0, 0, 0);
        acc[1][cf] = __builtin_amdgcn_mfma_f32_16x16x32_bf16(af[ks][1], bf[ks][cf], acc[1][cf], 0, 0, 0);
      }
    __builtin_amdgcn_s_setprio(0);
  }

#pragma unroll
  for(int rf = 0; rf < 2; ++rf)
#pragma unroll
    for(int cf = 0; cf < 2; ++cf){
      const int h = h0 + wc * 32 + cf * 16 + rl;
#pragma unroll
      for(int r = 0; r < 4; ++r){
        const int tl = wr * 32 + rf * 16 + kg * 4 + r;
        const size_t g = rowbase + tl;
        float num = acc[rf][cf][r], den = acc[rf][cf + 2][r];
        float q = Qsig[g * 128 + h];
        Yt[g * 128 + h] = f2bf(q * num / den);
      }
    }
}

// ---------------------------------------------------------------------------
// Kernel 5: output projection out = Yt @ Wp^T + bp. grid = 256, 256 threads.
// ---------------------------------------------------------------------------
__global__ __launch_bounds__(256) void outproj_kernel(
    const unsigned short* __restrict__ Yt, const float* __restrict__ Wp,
    const float* __restrict__ bp, float* __restrict__ out)
{
  __shared__ __align__(16) short As[64 * 32];
  __shared__ __align__(16) short Bs[256 * 32];
  const int g0 = blockIdx.x * 64;
  const int tid = threadIdx.x;
  const int w = tid >> 6, lane = tid & 63, rl = lane & 15, kg = lane >> 4;
  f32x4 acc[16];
  for(int i = 0; i < 16; i++) acc[i] = (f32x4){0.f, 0.f, 0.f, 0.f};

  const int ar = tid >> 2, apart = tid & 3;
  const int c = tid & 31, dr = tid >> 5;
  for(int k = 0; k < 128; k += 32){
    __syncthreads();
    *(uint4*)&As[ar * 32 + apart * 8] =
        *(const uint4*)(Yt + (size_t)(g0 + ar) * 128 + k + apart * 8);
    for(int p = 0; p < 32; p++){
      int d = dr + p * 8;
      Bs[d * 32 + c] = (short)f2bf(Wp[(size_t)d * 128 + k + c]);
    }
    __syncthreads();
    bf16x8 a = *(const bf16x8*)&As[(w * 16 + rl) * 32 + kg * 8];
    for(int cf = 0; cf < 16; cf++){
      bf16x8 bb = *(const bf16x8*)&Bs[(cf * 16 + rl) * 32 + kg * 8];
      acc[cf] = __builtin_amdgcn_mfma_f32_16x16x32_bf16(a, bb, acc[cf], 0, 0, 0);
    }
  }
  for(int cf = 0; cf < 16; cf++){
    int d = cf * 16 + rl;
    float bpd = bp[d];
    for(int r = 0; r < 4; r++){
      int tl = w * 16 + kg * 4 + r;
      out[(size_t)(g0 + tl) * 256 + d] = acc[cf][r] + bpd;
    }
  }
}

extern "C" void kernel_launch(void* const* d_in, const int* in_sizes, int n_in,
                              void* d_out, int out_size, void* d_ws, size_t ws_size,
                              hipStream_t stream)
{
  const float* x  = (const float*)d_in[0];
  const float* ab = (const float*)d_in[1];
  const float* Wq = (const float*)d_in[2];
  const float* bq = (const float*)d_in[3];
  const float* Wk = (const float*)d_in[4];
  const float* bk = (const float*)d_in[5];
  const float* Wv = (const float*)d_in[6];
  const float* bv = (const float*)d_in[7];
  const float* Wp = (const float*)d_in[8];
  const float* bp = (const float*)d_in[9];
  float* out = (float*)d_out;

  char* ws = (char*)d_ws;
  float* Qsig          = (float*)(ws);                     //  0.0 MB (8.4)
  float* Kt            = (float*)(ws + 8388608);           //  8.4 MB (8.4) -> Yt after colsm
  float* Vt            = (float*)(ws + 16777216);          // 16.8 MB (8.4)
  unsigned short* Mt   = (unsigned short*)(ws + 25165824); // 25.2 MB (8.4)
  unsigned short* eab  = (unsigned short*)(ws + 33554432); // 33.6 MB (67.1)
  unsigned short* Yt   = (unsigned short*)(ws + 8388608);  // reuse Kt slot (4.2)

  qkv_kernel<<<dim3(256, 3), 256, 0, stream>>>(x, Wq, bq, Wk, bk, Wv, bv, Qsig, Kt, Vt);
  colsm_kernel<<<256, 256, 0, stream>>>(Kt, Vt, Mt);
  softexp_kernel<<<16384, 256, 0, stream>>>(ab, eab);
  aft_gemm4<<<512, 256, 0, stream>>>(eab, Mt, Qsig, Yt);
  outproj_kernel<<<256, 256, 0, stream>>>(Yt, Wp, bp, out);
}